// Round 1
// baseline (117.147 us; speedup 1.0000x reference)
//
#include <hip/hip_runtime.h>

// Shapes (fixed by the reference):
//   frames: (4, 8, 256, 256, 1) f32
//   core:   (4, 256, 256, 200)  f32  -> raw-reshaped to (4, 8, 256, 256, 1, 25)
//   out:    pred_img (4,256,256,1) ++ pred_img_i (4,8,256,256,1), f32
#define H 256
#define W 256
#define NB 8
#define BS 4

// One thread computes 4 consecutive x-pixels of pred_img_i for one (b,n,y).
// Its 4*25 = 100 core weights are a contiguous, 16B-aligned 400B chunk
// -> 25 float4 loads (perfectly streamed, each byte read exactly once).
__global__ __launch_bounds__(256, 4)
void kpn_main(const float* __restrict__ frames, const float* __restrict__ core,
              float* __restrict__ pred_i) {
  int g = blockIdx.x * 256 + threadIdx.x;   // 0 .. 524287 (= 4*8*256*64)
  int x0 = (g & 63) << 2;                   // 0,4,...,252
  int y  = (g >> 6) & 255;
  int bn = g >> 14;                         // b*8 + n, 0..31
  const float*  fbase = frames + (size_t)bn * (H * W);
  const float4* c4    = (const float4*)(core + (size_t)g * 100);

  // 5x9 zero-padded frame neighborhood covering x0-2 .. x0+6
  float f[5][9];
#pragma unroll
  for (int i = 0; i < 5; ++i) {
    int yy = y + i - 2;
    bool yok = ((unsigned)yy < (unsigned)H);
    const float* fr = fbase + (size_t)(yok ? yy : 0) * W;
#pragma unroll
    for (int j = 0; j < 9; ++j) {
      int xx = x0 + j - 2;
      bool ok = yok && ((unsigned)xx < (unsigned)W);
      f[i][j] = ok ? fr[xx] : 0.0f;
    }
  }

  float acc[4] = {0.f, 0.f, 0.f, 0.f};
#pragma unroll
  for (int k = 0; k < 25; ++k) {
    float4 wv = c4[k];
    float wc[4] = {wv.x, wv.y, wv.z, wv.w};
#pragma unroll
    for (int c = 0; c < 4; ++c) {
      const int flat = 4 * k + c;     // 0..99, all compile-time after unroll
      const int p    = flat / 25;     // which of the 4 pixels
      const int kidx = flat % 25;     // kernel tap
      const int ki   = kidx / 5;
      const int kj   = kidx % 5;
      acc[p] += wc[c] * f[ki][p + kj];
    }
  }

  *(float4*)(pred_i + (size_t)g * 4) = make_float4(acc[0], acc[1], acc[2], acc[3]);
}

// pred_img = mean over n of pred_img_i. One thread per 4 x-pixels of (b,y).
__global__ __launch_bounds__(256)
void kpn_mean(const float* __restrict__ pred_i, float* __restrict__ pred) {
  int g = blockIdx.x * 256 + threadIdx.x;   // 0 .. 65535 (= 4*256*64)
  int b  = g >> 14;
  int yx = g & 16383;                       // y*64 + x4
  const float4* src = (const float4*)pred_i + (size_t)b * (NB * 16384) + yx;
  float4 s = make_float4(0.f, 0.f, 0.f, 0.f);
#pragma unroll
  for (int n = 0; n < NB; ++n) {
    float4 v = src[(size_t)n * 16384];
    s.x += v.x; s.y += v.y; s.z += v.z; s.w += v.w;
  }
  s.x *= 0.125f; s.y *= 0.125f; s.z *= 0.125f; s.w *= 0.125f;
  ((float4*)pred)[g] = s;
}

extern "C" void kernel_launch(void* const* d_in, const int* in_sizes, int n_in,
                              void* d_out, int out_size, void* d_ws, size_t ws_size,
                              hipStream_t stream) {
  const float* frames = (const float*)d_in[0];
  const float* core   = (const float*)d_in[1];
  float* pred   = (float*)d_out;                 // (4,256,256,1)
  float* pred_i = pred + (size_t)BS * H * W;     // (4,8,256,256,1)

  hipLaunchKernelGGL(kpn_main, dim3(2048), dim3(256), 0, stream,
                     frames, core, pred_i);
  hipLaunchKernelGGL(kpn_mean, dim3(256), dim3(256), 0, stream,
                     pred_i, pred);
}

// Round 2
// 42.702 us; speedup vs baseline: 2.7434x; 2.7434x over previous
//
#include <hip/hip_runtime.h>

// Shapes (fixed by the reference):
//   frames: (4, 8, 256, 256, 1) f32
//   core:   (4, 256, 256, 200)  f32  -> raw-reshaped to (4, 8, 256, 256, 1, 25)
//   out:    pred_img (4,256,256,1) ++ pred_img_i (4,8,256,256,1), f32
#define H 256
#define W 256
#define NB 8
#define BS 4

// Block = 256 threads = one (b,n) x 4 consecutive y-rows x all x.
// Thread owns 4 consecutive x-pixels; its 100 core weights are one
// contiguous 400B (16B-aligned) chunk -> 25 float4 loads, all issued
// up-front for max memory-level parallelism. Frames staged in LDS.
__global__ __launch_bounds__(256, 3)
void kpn_main(const float* __restrict__ frames, const float* __restrict__ core,
              float* __restrict__ pred_i) {
  __shared__ float lds[8][264];   // rows y0-2..y0+5, cols lx = x+4, x in [-4,259]

  const int tid = threadIdx.x;
  const int blk = blockIdx.x;
  const int g   = blk * 256 + tid;           // global 4-pixel-group id
  const int bn  = g >> 14;                   // b*8+n, constant per block
  const int y0  = (blk & 63) * 4;            // first y row of this block

  // ---- issue ALL 25 core loads first (hide HBM latency under staging) ----
  const float4* c4 = (const float4*)(core + (size_t)g * 100);
  float ws[100];
#pragma unroll
  for (int k = 0; k < 25; ++k) {
    float4 t = c4[k];
    ws[4 * k + 0] = t.x; ws[4 * k + 1] = t.y;
    ws[4 * k + 2] = t.z; ws[4 * k + 3] = t.w;
  }

  // ---- cooperative frame staging: 8 rows x 256 floats (+ zero halos) ----
  const float* fbase = frames + (size_t)bn * (H * W);
  {
    const int r  = tid >> 5;                 // 0..7
    const int c  = tid & 31;                 // 0..31, 8 floats each
    const int yy = y0 + r - 2;
    float4 z  = make_float4(0.f, 0.f, 0.f, 0.f);
    float4 v0 = z, v1 = z;
    if ((unsigned)yy < (unsigned)H) {
      const float4* src = (const float4*)(fbase + (size_t)yy * W + c * 8);
      v0 = src[0]; v1 = src[1];
    }
    float* dst = &lds[r][c * 8 + 4];
    *(float4*)(dst)     = v0;
    *(float4*)(dst + 4) = v1;
    if (c == 0)  *(float4*)(&lds[r][0])   = z;   // x = -4..-1
    if (c == 31) *(float4*)(&lds[r][260]) = z;   // x = 256..259
  }
  __syncthreads();

  // ---- compute: 25 taps x 4 pixels ----
  const int x0 = (tid & 63) * 4;
  const int yl = tid >> 6;                   // 0..3
  float acc[4] = {0.f, 0.f, 0.f, 0.f};
#pragma unroll
  for (int ki = 0; ki < 5; ++ki) {
    const float4* lrow = (const float4*)&lds[yl + ki][x0];  // 16B-aligned
    float4 a0 = lrow[0], a1 = lrow[1], a2 = lrow[2];        // x = x0-4..x0+7
    float fr[12] = {a0.x, a0.y, a0.z, a0.w,
                    a1.x, a1.y, a1.z, a1.w,
                    a2.x, a2.y, a2.z, a2.w};
#pragma unroll
    for (int kj = 0; kj < 5; ++kj) {
      const int kidx = ki * 5 + kj;
#pragma unroll
      for (int p = 0; p < 4; ++p) {
        // weight for pixel p, tap kidx sits at flat index p*25+kidx
        acc[p] += ws[p * 25 + kidx] * fr[p + kj + 2];
      }
    }
  }
  *(float4*)(pred_i + (size_t)g * 4) = make_float4(acc[0], acc[1], acc[2], acc[3]);
}

// pred_img = mean over n of pred_img_i. One thread per 4 x-pixels of (b,y).
__global__ __launch_bounds__(256)
void kpn_mean(const float* __restrict__ pred_i, float* __restrict__ pred) {
  int g = blockIdx.x * 256 + threadIdx.x;   // 0 .. 65535 (= 4*256*64)
  int b  = g >> 14;
  int yx = g & 16383;                       // y*64 + x4
  const float4* src = (const float4*)pred_i + (size_t)b * (NB * 16384) + yx;
  float4 s = make_float4(0.f, 0.f, 0.f, 0.f);
#pragma unroll
  for (int n = 0; n < NB; ++n) {
    float4 v = src[(size_t)n * 16384];
    s.x += v.x; s.y += v.y; s.z += v.z; s.w += v.w;
  }
  s.x *= 0.125f; s.y *= 0.125f; s.z *= 0.125f; s.w *= 0.125f;
  ((float4*)pred)[g] = s;
}

extern "C" void kernel_launch(void* const* d_in, const int* in_sizes, int n_in,
                              void* d_out, int out_size, void* d_ws, size_t ws_size,
                              hipStream_t stream) {
  const float* frames = (const float*)d_in[0];
  const float* core   = (const float*)d_in[1];
  float* pred   = (float*)d_out;                 // (4,256,256,1)
  float* pred_i = pred + (size_t)BS * H * W;     // (4,8,256,256,1)

  hipLaunchKernelGGL(kpn_main, dim3(2048), dim3(256), 0, stream,
                     frames, core, pred_i);
  hipLaunchKernelGGL(kpn_mean, dim3(256), dim3(256), 0, stream,
                     pred_i, pred);
}